// Round 1
// baseline (649.560 us; speedup 1.0000x reference)
//
#include <hip/hip_runtime.h>

// SwitchPolicyValueNetwork: pre-GEMM+tanh -> grouped expert GEMM (selected
// expert only, via counting-sort bucketing) + tanh -> post-GEMM + tanh.
// bf16 MFMA compute (threshold permits), fp32 accumulate.
//
// ws layout: X1 bf16 [4096x2048] @0, Z bf16 [4096x2048] @16MB,
//            offs int[17] @32MB, rows int[4096] @32MB+128. Total ~33.6MB.

#define Bsz 4096
#define INd 1024
#define Hd  2048
#define OUTd 1024
#define NEXP 16

#define BM 128
#define BN 128
#define BK 32
#define LDT 56   // LDS row stride (bf16 elems) = 112B: 16B-aligned, 2-way bank alias only

typedef short bf16x8 __attribute__((ext_vector_type(8)));
typedef float f32x4 __attribute__((ext_vector_type(4)));
typedef unsigned short u16;

__device__ __forceinline__ u16 f2bf(float f) {
  unsigned u = __float_as_uint(f);
  u += 0x7FFF + ((u >> 16) & 1);   // RNE
  return (u16)(u >> 16);
}

__device__ __forceinline__ float fast_tanh(float x) {
  float ax = fabsf(x);
  float e = __expf(2.0f * ax);     // inf for large ax -> t -> 1 (safe)
  float t = 1.0f - 2.0f / (e + 1.0f);
  return x < 0.0f ? -t : t;
}

// One BK step: read A/B fragments from LDS, 16 MFMAs per wave.
// A-frag: lane holds A[m=lane&15][k=(lane>>4)*8 + j]; B-frag mirrors with n=lane&15.
__device__ __forceinline__ void mfma_step(const u16* As, const u16* Bs,
                                          int wm, int wn, int fr, int fk,
                                          f32x4 acc[4][4]) {
  bf16x8 af[4], bq[4];
#pragma unroll
  for (int i = 0; i < 4; ++i) af[i] = *(const bf16x8*)&As[(wm + 16 * i + fr) * LDT + fk];
#pragma unroll
  for (int j = 0; j < 4; ++j) bq[j] = *(const bf16x8*)&Bs[(wn + 16 * j + fr) * LDT + fk];
#pragma unroll
  for (int i = 0; i < 4; ++i)
#pragma unroll
    for (int j = 0; j < 4; ++j)
      acc[i][j] = __builtin_amdgcn_mfma_f32_16x16x32_bf16(af[i], bq[j], acc[i][j], 0, 0, 0);
}

// ---------------- bucketing (counting sort by expert), single block ----------------
__global__ __launch_bounds__(256) void k_bucket(const int* __restrict__ idx,
                                                int* __restrict__ offs,
                                                int* __restrict__ rows) {
  __shared__ int cnt[NEXP];
  __shared__ int base[NEXP];
  int t = threadIdx.x;
  if (t < NEXP) cnt[t] = 0;
  __syncthreads();
  for (int b = t; b < Bsz; b += 256) atomicAdd(&cnt[idx[b]], 1);
  __syncthreads();
  if (t == 0) {
    int s = 0;
    for (int e = 0; e < NEXP; ++e) { base[e] = s; offs[e] = s; s += cnt[e]; }
    offs[NEXP] = s;
  }
  __syncthreads();
  for (int b = t; b < Bsz; b += 256) {
    int e = idx[b];
    int p = atomicAdd(&base[e], 1);
    rows[p] = b;
  }
}

// ---------------- GEMM1: X1 = tanh(obs @ pre_w^T + pre_b), bf16 out ----------------
__global__ __launch_bounds__(256) void k_pre(const float* __restrict__ obs,
                                             const float* __restrict__ pre_w,
                                             const float* __restrict__ pre_b,
                                             u16* __restrict__ X1) {
  __shared__ u16 As[BM * LDT];
  __shared__ u16 Bs[BN * LDT];
  const int n0 = blockIdx.x * BN;
  const int m0 = blockIdx.y * BM;
  const int tid = threadIdx.x;
  const int lane = tid & 63;
  const int wv = tid >> 6;
  const int wm = (wv >> 1) * 64, wn = (wv & 1) * 64;
  const int fr = lane & 15, fq = lane >> 4;
  const int fk = fq * 8;
  const int sr = tid >> 3;          // 0..31
  const int skc = (tid & 7) * 4;    // 0..28 (floats)

  f32x4 acc[4][4] = {};

  for (int k0 = 0; k0 < INd; k0 += BK) {
#pragma unroll
    for (int p = 0; p < 4; ++p) {
      int row = sr + 32 * p;
      float4 va = *(const float4*)&obs[(size_t)(m0 + row) * INd + k0 + skc];
      ushort4 ha; ha.x = f2bf(va.x); ha.y = f2bf(va.y); ha.z = f2bf(va.z); ha.w = f2bf(va.w);
      *(ushort4*)&As[row * LDT + skc] = ha;
      float4 vb = *(const float4*)&pre_w[(size_t)(n0 + row) * INd + k0 + skc];
      ushort4 hb; hb.x = f2bf(vb.x); hb.y = f2bf(vb.y); hb.z = f2bf(vb.z); hb.w = f2bf(vb.w);
      *(ushort4*)&Bs[row * LDT + skc] = hb;
    }
    __syncthreads();
    mfma_step(As, Bs, wm, wn, fr, fk, acc);
    __syncthreads();
  }
#pragma unroll
  for (int j = 0; j < 4; ++j) {
    int col = n0 + wn + 16 * j + fr;
    float bias = pre_b[col];
#pragma unroll
    for (int i = 0; i < 4; ++i) {
      int rb = m0 + wm + 16 * i + fq * 4;
#pragma unroll
      for (int r = 0; r < 4; ++r)
        X1[(size_t)(rb + r) * Hd + col] = f2bf(fast_tanh(acc[i][j][r] + bias));
    }
  }
}

// ------- GEMM2 (grouped): Z[row] = tanh(X1[row] @ W_e^T + b_e) for bucketed rows -------
__global__ __launch_bounds__(256) void k_expert(const u16* __restrict__ X1,
                                                const float* __restrict__ ew,
                                                const float* __restrict__ eb,
                                                const int* __restrict__ offs,
                                                const int* __restrict__ rows,
                                                u16* __restrict__ Z) {
  __shared__ u16 As[BM * LDT];
  __shared__ u16 Bs[BN * LDT];
  const int e = blockIdx.y >> 5;
  const int rt = blockIdx.y & 31;
  const int seg = offs[e];
  const int cnt = offs[e + 1] - seg;
  const int tbase = rt * BM;
  if (tbase >= cnt) return;                 // block-uniform early exit
  const int nval = min(BM, cnt - tbase);
  const int n0 = blockIdx.x * BN;
  const float* We = ew + (size_t)e * Hd * Hd;

  const int tid = threadIdx.x;
  const int lane = tid & 63;
  const int wv = tid >> 6;
  const int wm = (wv >> 1) * 64, wn = (wv & 1) * 64;
  const int fr = lane & 15, fq = lane >> 4;
  const int fk = fq * 8;

  // A staging: bf16 16B copies. thread -> (row, 8-elem chunk)
  const int ar_ = tid >> 2;                 // 0..63
  const int akc = (tid & 3) * 8;            // bf16 elems
  int rowg[2];
#pragma unroll
  for (int p = 0; p < 2; ++p) {
    int ar = ar_ + 64 * p;
    rowg[p] = (ar < nval) ? rows[seg + tbase + ar] : -1;
  }
  // B staging: fp32->bf16 convert
  const int sr = tid >> 3;
  const int skc = (tid & 7) * 4;

  f32x4 acc[4][4] = {};
  const float4 zero4 = {0.f, 0.f, 0.f, 0.f};

  for (int k0 = 0; k0 < Hd; k0 += BK) {
#pragma unroll
    for (int p = 0; p < 2; ++p) {
      int ar = ar_ + 64 * p;
      float4 v = (rowg[p] >= 0) ? *(const float4*)&X1[(size_t)rowg[p] * Hd + k0 + akc] : zero4;
      *(float4*)&As[ar * LDT + akc] = v;    // raw copy of 8 bf16
    }
#pragma unroll
    for (int p = 0; p < 4; ++p) {
      int row = sr + 32 * p;
      float4 vb = *(const float4*)&We[(size_t)(n0 + row) * Hd + k0 + skc];
      ushort4 hb; hb.x = f2bf(vb.x); hb.y = f2bf(vb.y); hb.z = f2bf(vb.z); hb.w = f2bf(vb.w);
      *(ushort4*)&Bs[row * LDT + skc] = hb;
    }
    __syncthreads();
    mfma_step(As, Bs, wm, wn, fr, fk, acc);
    __syncthreads();
  }
#pragma unroll
  for (int i = 0; i < 4; ++i) {
#pragma unroll
    for (int r = 0; r < 4; ++r) {
      int arow = wm + 16 * i + fq * 4 + r;
      if (arow < nval) {
        int orow = rows[seg + tbase + arow];
#pragma unroll
        for (int j = 0; j < 4; ++j) {
          int col = n0 + wn + 16 * j + fr;
          float bias = eb[(size_t)e * Hd + col];
          Z[(size_t)orow * Hd + col] = f2bf(fast_tanh(acc[i][j][r] + bias));
        }
      }
    }
  }
}

// ---------------- GEMM3: out = tanh(Z @ post_w^T + post_b), fp32 out ----------------
__global__ __launch_bounds__(256) void k_post(const u16* __restrict__ Z,
                                              const float* __restrict__ pw,
                                              const float* __restrict__ pb,
                                              float* __restrict__ out) {
  __shared__ u16 As[BM * LDT];
  __shared__ u16 Bs[BN * LDT];
  const int n0 = blockIdx.x * BN;
  const int m0 = blockIdx.y * BM;
  const int tid = threadIdx.x;
  const int lane = tid & 63;
  const int wv = tid >> 6;
  const int wm = (wv >> 1) * 64, wn = (wv & 1) * 64;
  const int fr = lane & 15, fq = lane >> 4;
  const int fk = fq * 8;
  const int ar_ = tid >> 2;
  const int akc = (tid & 3) * 8;
  const int sr = tid >> 3;
  const int skc = (tid & 7) * 4;

  f32x4 acc[4][4] = {};

  for (int k0 = 0; k0 < Hd; k0 += BK) {
#pragma unroll
    for (int p = 0; p < 2; ++p) {
      int ar = ar_ + 64 * p;
      float4 v = *(const float4*)&Z[(size_t)(m0 + ar) * Hd + k0 + akc];
      *(float4*)&As[ar * LDT + akc] = v;
    }
#pragma unroll
    for (int p = 0; p < 4; ++p) {
      int row = sr + 32 * p;
      float4 vb = *(const float4*)&pw[(size_t)(n0 + row) * Hd + k0 + skc];
      ushort4 hb; hb.x = f2bf(vb.x); hb.y = f2bf(vb.y); hb.z = f2bf(vb.z); hb.w = f2bf(vb.w);
      *(ushort4*)&Bs[row * LDT + skc] = hb;
    }
    __syncthreads();
    mfma_step(As, Bs, wm, wn, fr, fk, acc);
    __syncthreads();
  }
#pragma unroll
  for (int j = 0; j < 4; ++j) {
    int col = n0 + wn + 16 * j + fr;
    float bias = pb[col];
#pragma unroll
    for (int i = 0; i < 4; ++i) {
      int rb = m0 + wm + 16 * i + fq * 4;
#pragma unroll
      for (int r = 0; r < 4; ++r)
        out[(size_t)(rb + r) * OUTd + col] = fast_tanh(acc[i][j][r] + bias);
    }
  }
}

extern "C" void kernel_launch(void* const* d_in, const int* in_sizes, int n_in,
                              void* d_out, int out_size, void* d_ws, size_t ws_size,
                              hipStream_t stream) {
  const float* obs   = (const float*)d_in[0];
  const int*   sw    = (const int*)d_in[1];
  const float* pre_w = (const float*)d_in[2];
  const float* pre_b = (const float*)d_in[3];
  const float* ew    = (const float*)d_in[4];
  const float* eb    = (const float*)d_in[5];
  const float* pw    = (const float*)d_in[6];
  const float* pb    = (const float*)d_in[7];
  float* out = (float*)d_out;

  char* ws = (char*)d_ws;
  u16* X1   = (u16*)ws;
  u16* Z    = (u16*)(ws + (size_t)Bsz * Hd * 2);
  int* offs = (int*)(ws + (size_t)2 * Bsz * Hd * 2);
  int* rows = offs + 32;

  k_bucket<<<dim3(1), dim3(256), 0, stream>>>(sw, offs, rows);
  k_pre<<<dim3(Hd / BN, Bsz / BM), dim3(256), 0, stream>>>(obs, pre_w, pre_b, X1);
  k_expert<<<dim3(Hd / BN, NEXP * 32), dim3(256), 0, stream>>>(X1, ew, eb, offs, rows, Z);
  k_post<<<dim3(OUTd / BN, Bsz / BM), dim3(256), 0, stream>>>(Z, pw, pb, out);
}

// Round 2
// 629.339 us; speedup vs baseline: 1.0321x; 1.0321x over previous
//
#include <hip/hip_runtime.h>

// SwitchPolicyValueNetwork — round 2.
// Pipeline: bucket rows by expert -> cvt weights/obs to bf16 -> 3 bf16 MFMA GEMMs
// (m97-style global_load_lds async staging, BK=64, LDS double-buffer, 1 barrier/iter,
//  XOR-swizzled LDS chunks since global_load_lds forbids padding).
//
// ws tiers (host-side, deterministic per ws_size):
//   full (>=176MB): everything bf16-preconverted incl. expert_w
//   mid  (>=48MB):  obs/pre_w/post_w preconverted; expert B staged fp32 sync w/ reg prefetch
//   low:            no preconvert; fp32 sync staging w/ reg prefetch (A of expert/post still async bf16)

#define Bsz 4096
#define INd 1024
#define Hd  2048
#define OUTd 1024
#define NEXP 16

typedef short bf16x8 __attribute__((ext_vector_type(8)));
typedef float f32x4 __attribute__((ext_vector_type(4)));
typedef unsigned short u16;

__device__ __forceinline__ u16 f2bf(float f) {
  unsigned u = __float_as_uint(f);
  u += 0x7FFF + ((u >> 16) & 1);   // RNE
  return (u16)(u >> 16);
}

__device__ __forceinline__ float fast_tanh(float x) {
  float ax = fabsf(x);
  float e = __expf(2.0f * ax);     // inf for large ax -> t -> 1 (safe)
  float t = 1.0f - 2.0f / (e + 1.0f);
  return x < 0.0f ? -t : t;
}

// async 16B global->LDS (direct, no VGPR round-trip)
#define GLL16(g, l)                                                            \
  __builtin_amdgcn_global_load_lds(                                            \
      (const __attribute__((address_space(1))) unsigned int*)(g),              \
      (__attribute__((address_space(3))) unsigned int*)(l), 16, 0, 0)

// ---- staging: 128-row bf16 tile, BK=64 (row = 128B = 8 x 16B chunks) ----
// thread t -> slot (row = t>>3 (+32p), c = t&7); slot c holds global chunk c^(row&7)
// LDS dest = base + (t + 256p)*16 B  (wave-uniform base + lane*16 — required by HW)
__device__ __forceinline__ void stage128(const u16* gbase, int ldk, u16* lds, int t) {
  const int row = t >> 3;
  const int gc8 = ((t & 7) ^ (row & 7)) << 3;
#pragma unroll
  for (int p = 0; p < 4; ++p)
    GLL16(gbase + (size_t)(row + 32 * p) * ldk + gc8, lds + ((t + 256 * p) << 3));
}

__device__ __forceinline__ void stage64(const u16* gbase, int ldk, u16* lds, int t) {
  const int row = t >> 3;
  const int gc8 = ((t & 7) ^ (row & 7)) << 3;
#pragma unroll
  for (int p = 0; p < 2; ++p)
    GLL16(gbase + (size_t)(row + 32 * p) * ldk + gc8, lds + ((t + 256 * p) << 3));
}

// gathered A tile (expert): per-lane global row, tail lanes read a zeroed chunk
__device__ __forceinline__ void stage_gather(const u16* X1k, const int rowg[4],
                                             const u16* zeroc, u16* lds, int t) {
  const int gc8 = ((t & 7) ^ ((t >> 3) & 7)) << 3;
#pragma unroll
  for (int p = 0; p < 4; ++p) {
    const u16* g = (rowg[p] >= 0) ? X1k + (size_t)rowg[p] * Hd + gc8 : zeroc;
    GLL16(g, lds + ((t + 256 * p) << 3));
  }
}

// ---- fallback: fp32 128-row tile, register prefetch + convert + swizzled ds_write ----
struct F32Tile { float4 v[8]; };
__device__ __forceinline__ void loadF32tile(const float* W, int ldk, int t, F32Tile& r) {
  const int brow = t & 127, half = t >> 7;
  const float* p = W + (size_t)brow * ldk + (half << 5);
#pragma unroll
  for (int q = 0; q < 8; ++q) r.v[q] = *(const float4*)(p + 4 * q);
}
__device__ __forceinline__ void writeF32tile(const F32Tile& r, u16* lds, int t) {
  const int brow = t & 127, half = t >> 7;
#pragma unroll
  for (int q2 = 0; q2 < 4; ++q2) {
    const float4 x = r.v[2 * q2], y = r.v[2 * q2 + 1];
    bf16x8 o;
    o[0] = (short)f2bf(x.x); o[1] = (short)f2bf(x.y);
    o[2] = (short)f2bf(x.z); o[3] = (short)f2bf(x.w);
    o[4] = (short)f2bf(y.x); o[5] = (short)f2bf(y.y);
    o[6] = (short)f2bf(y.z); o[7] = (short)f2bf(y.w);
    const int gq = (half << 2) + q2;
    const int c = gq ^ (brow & 7);
    *(bf16x8*)&lds[brow * 64 + (c << 3)] = o;
  }
}

// ---- compute one BK=64 tile: 2 k-steps x (MI x 4) MFMAs ----
template <int MI>
__device__ __forceinline__ void compute_tile(const u16* As, const u16* Bs,
                                             int wm, int wn, int fr, int fq,
                                             f32x4 (&acc)[MI][4]) {
#pragma unroll
  for (int ks = 0; ks < 2; ++ks) {
    const int ch = (((ks << 2) + fq) ^ (fr & 7)) << 3;   // swizzled 16B chunk
    bf16x8 af[MI], bq[4];
#pragma unroll
    for (int i = 0; i < MI; ++i) af[i] = *(const bf16x8*)&As[(wm + 16 * i + fr) * 64 + ch];
#pragma unroll
    for (int j = 0; j < 4; ++j) bq[j] = *(const bf16x8*)&Bs[(wn + 16 * j + fr) * 64 + ch];
#pragma unroll
    for (int i = 0; i < MI; ++i)
#pragma unroll
      for (int j = 0; j < 4; ++j)
        acc[i][j] = __builtin_amdgcn_mfma_f32_16x16x32_bf16(af[i], bq[j], acc[i][j], 0, 0, 0);
  }
}

// ---------------- bucketing + zero-chunk init ----------------
__global__ __launch_bounds__(256) void k_bucket(const int* __restrict__ idx,
                                                int* __restrict__ offs,
                                                int* __restrict__ rows,
                                                int* __restrict__ zc) {
  __shared__ int cnt[NEXP];
  __shared__ int base[NEXP];
  int t = threadIdx.x;
  if (t < 16) zc[t] = 0;
  if (t < NEXP) cnt[t] = 0;
  __syncthreads();
  for (int b = t; b < Bsz; b += 256) atomicAdd(&cnt[idx[b]], 1);
  __syncthreads();
  if (t == 0) {
    int s = 0;
    for (int e = 0; e < NEXP; ++e) { base[e] = s; offs[e] = s; s += cnt[e]; }
    offs[NEXP] = s;
  }
  __syncthreads();
  for (int b = t; b < Bsz; b += 256) {
    int e = idx[b];
    int p = atomicAdd(&base[e], 1);
    rows[p] = b;
  }
}

// ---------------- fp32 -> bf16 streaming convert ----------------
__global__ __launch_bounds__(256) void k_cvt(const float* __restrict__ src,
                                             u16* __restrict__ dst, int n) {
  int i = (blockIdx.x * 256 + threadIdx.x) * 8;
  if (i >= n) return;
  float4 a = *(const float4*)(src + i);
  float4 b = *(const float4*)(src + i + 4);
  bf16x8 o;
  o[0] = (short)f2bf(a.x); o[1] = (short)f2bf(a.y);
  o[2] = (short)f2bf(a.z); o[3] = (short)f2bf(a.w);
  o[4] = (short)f2bf(b.x); o[5] = (short)f2bf(b.y);
  o[6] = (short)f2bf(b.z); o[7] = (short)f2bf(b.w);
  *(bf16x8*)(dst + i) = o;
}

// ---------------- GEMM1: X1 = tanh(obs @ pre_w^T + pre_b) ----------------
template <bool PC>
__global__ __launch_bounds__(256) void k_pre_t(const float* __restrict__ obs32,
                                               const u16* __restrict__ obsb,
                                               const float* __restrict__ prew32,
                                               const u16* __restrict__ prewb,
                                               const float* __restrict__ pre_b,
                                               u16* __restrict__ X1) {
  __shared__ u16 As[2][128 * 64];
  __shared__ u16 Bs[2][128 * 64];
  const int tid = threadIdx.x, lane = tid & 63, wv = tid >> 6;
  const int wm = (wv >> 1) << 6, wn = (wv & 1) << 6;
  const int fr = lane & 15, fq = lane >> 4;
  const int n0 = blockIdx.x * 128, m0 = blockIdx.y * 128;
  f32x4 acc[4][4] = {};
  const int NT = INd / 64;

  if constexpr (PC) {
    stage128(obsb + (size_t)m0 * INd, INd, As[0], tid);
    stage128(prewb + (size_t)n0 * INd, INd, Bs[0], tid);
    __syncthreads();
    for (int kt = 0; kt < NT; ++kt) {
      const int nb = (kt + 1) & 1;
      if (kt + 1 < NT) {
        stage128(obsb + (size_t)m0 * INd + (kt + 1) * 64, INd, As[nb], tid);
        stage128(prewb + (size_t)n0 * INd + (kt + 1) * 64, INd, Bs[nb], tid);
      }
      compute_tile<4>(As[kt & 1], Bs[kt & 1], wm, wn, fr, fq, acc);
      __syncthreads();
    }
  } else {
    F32Tile ra, rb;
    loadF32tile(obs32 + (size_t)m0 * INd, INd, tid, ra);
    loadF32tile(prew32 + (size_t)n0 * INd, INd, tid, rb);
    writeF32tile(ra, As[0], tid);
    writeF32tile(rb, Bs[0], tid);
    __syncthreads();
    for (int kt = 0; kt < NT; ++kt) {
      const int nb = (kt + 1) & 1;
      const bool more = (kt + 1) < NT;
      F32Tile na, nbv;
      if (more) {
        loadF32tile(obs32 + (size_t)m0 * INd + (kt + 1) * 64, INd, tid, na);
        loadF32tile(prew32 + (size_t)n0 * INd + (kt + 1) * 64, INd, tid, nbv);
      }
      compute_tile<4>(As[kt & 1], Bs[kt & 1], wm, wn, fr, fq, acc);
      if (more) { writeF32tile(na, As[nb], tid); writeF32tile(nbv, Bs[nb], tid); }
      __syncthreads();
    }
  }

#pragma unroll
  for (int j = 0; j < 4; ++j) {
    int col = n0 + wn + 16 * j + fr;
    float bias = pre_b[col];
#pragma unroll
    for (int i = 0; i < 4; ++i) {
      int rb2 = m0 + wm + 16 * i + fq * 4;
#pragma unroll
      for (int r = 0; r < 4; ++r)
        X1[(size_t)(rb2 + r) * Hd + col] = f2bf(fast_tanh(acc[i][j][r] + bias));
    }
  }
}

// ------- GEMM2 (grouped): Z[row] = tanh(X1[row] @ W_e^T + b_e) -------
template <bool PC>
__global__ __launch_bounds__(256) void k_expert_t(const u16* __restrict__ X1,
                                                  const float* __restrict__ ew32,
                                                  const u16* __restrict__ ewb,
                                                  const float* __restrict__ eb,
                                                  const int* __restrict__ offs,
                                                  const int* __restrict__ rows,
                                                  const u16* __restrict__ zeroc,
                                                  u16* __restrict__ Z) {
  const int e = blockIdx.y >> 5, rt = blockIdx.y & 31;
  const int seg = offs[e], cnt = offs[e + 1] - seg;
  const int tbase = rt * 128;
  if (tbase >= cnt) return;                 // block-uniform early exit
  const int nval = min(128, cnt - tbase);
  const int n0 = blockIdx.x * 128;

  __shared__ u16 As[2][128 * 64];
  __shared__ u16 Bs[2][128 * 64];
  const int tid = threadIdx.x, lane = tid & 63, wv = tid >> 6;
  const int wm = (wv >> 1) << 6, wn = (wv & 1) << 6;
  const int fr = lane & 15, fq = lane >> 4;

  int rowg[4];
  {
    const int r0 = tid >> 3;
#pragma unroll
    for (int p = 0; p < 4; ++p) {
      int ar = r0 + 32 * p;
      rowg[p] = (ar < nval) ? rows[seg + tbase + ar] : -1;
    }
  }
  f32x4 acc[4][4] = {};
  const int NT = Hd / 64;

  if constexpr (PC) {
    const u16* We = ewb + (size_t)e * Hd * Hd + (size_t)n0 * Hd;
    stage_gather(X1, rowg, zeroc, As[0], tid);
    stage128(We, Hd, Bs[0], tid);
    __syncthreads();
    for (int kt = 0; kt < NT; ++kt) {
      const int nb = (kt + 1) & 1;
      if (kt + 1 < NT) {
        stage_gather(X1 + (kt + 1) * 64, rowg, zeroc, As[nb], tid);
        stage128(We + (kt + 1) * 64, Hd, Bs[nb], tid);
      }
      compute_tile<4>(As[kt & 1], Bs[kt & 1], wm, wn, fr, fq, acc);
      __syncthreads();
    }
  } else {
    const float* We32 = ew32 + (size_t)e * Hd * Hd + (size_t)n0 * Hd;
    stage_gather(X1, rowg, zeroc, As[0], tid);
    {
      F32Tile rb;
      loadF32tile(We32, Hd, tid, rb);
      writeF32tile(rb, Bs[0], tid);
    }
    __syncthreads();
    for (int kt = 0; kt < NT; ++kt) {
      const int nb = (kt + 1) & 1;
      const bool more = (kt + 1) < NT;
      F32Tile rn;
      if (more) {
        stage_gather(X1 + (kt + 1) * 64, rowg, zeroc, As[nb], tid);
        loadF32tile(We32 + (kt + 1) * 64, Hd, tid, rn);
      }
      compute_tile<4>(As[kt & 1], Bs[kt & 1], wm, wn, fr, fq, acc);
      if (more) writeF32tile(rn, Bs[nb], tid);
      __syncthreads();
    }
  }

#pragma unroll
  for (int i = 0; i < 4; ++i) {
#pragma unroll
    for (int r = 0; r < 4; ++r) {
      int arow = wm + 16 * i + fq * 4 + r;
      if (arow < nval) {
        int orow = rows[seg + tbase + arow];
#pragma unroll
        for (int j = 0; j < 4; ++j) {
          int col = n0 + wn + 16 * j + fr;
          float bias = eb[(size_t)e * Hd + col];
          Z[(size_t)orow * Hd + col] = f2bf(fast_tanh(acc[i][j][r] + bias));
        }
      }
    }
  }
}

// ---------------- GEMM3: out = tanh(Z @ post_w^T + post_b), BM=64 ----------------
template <bool PC>
__global__ __launch_bounds__(256) void k_post_t(const u16* __restrict__ Z,
                                                const float* __restrict__ pw32,
                                                const u16* __restrict__ pwb,
                                                const float* __restrict__ pb,
                                                float* __restrict__ out) {
  __shared__ u16 As[2][64 * 64];
  __shared__ u16 Bs[2][128 * 64];
  const int tid = threadIdx.x, lane = tid & 63, wv = tid >> 6;
  const int wm = (wv >> 1) << 5, wn = (wv & 1) << 6;   // wave tile 32x64
  const int fr = lane & 15, fq = lane >> 4;
  const int n0 = blockIdx.x * 128, m0 = blockIdx.y * 64;
  f32x4 acc[2][4] = {};
  const int NT = Hd / 64;

  if constexpr (PC) {
    stage64(Z + (size_t)m0 * Hd, Hd, As[0], tid);
    stage128(pwb + (size_t)n0 * Hd, Hd, Bs[0], tid);
    __syncthreads();
    for (int kt = 0; kt < NT; ++kt) {
      const int nb = (kt + 1) & 1;
      if (kt + 1 < NT) {
        stage64(Z + (size_t)m0 * Hd + (kt + 1) * 64, Hd, As[nb], tid);
        stage128(pwb + (size_t)n0 * Hd + (kt + 1) * 64, Hd, Bs[nb], tid);
      }
      compute_tile<2>(As[kt & 1], Bs[kt & 1], wm, wn, fr, fq, acc);
      __syncthreads();
    }
  } else {
    stage64(Z + (size_t)m0 * Hd, Hd, As[0], tid);
    {
      F32Tile rb;
      loadF32tile(pw32 + (size_t)n0 * Hd, Hd, tid, rb);
      writeF32tile(rb, Bs[0], tid);
    }
    __syncthreads();
    for (int kt = 0; kt < NT; ++kt) {
      const int nb = (kt + 1) & 1;
      const bool more = (kt + 1) < NT;
      F32Tile rn;
      if (more) {
        stage64(Z + (size_t)m0 * Hd + (kt + 1) * 64, Hd, As[nb], tid);
        loadF32tile(pw32 + (size_t)n0 * Hd + (kt + 1) * 64, Hd, tid, rn);
      }
      compute_tile<2>(As[kt & 1], Bs[kt & 1], wm, wn, fr, fq, acc);
      if (more) writeF32tile(rn, Bs[nb], tid);
      __syncthreads();
    }
  }

#pragma unroll
  for (int j = 0; j < 4; ++j) {
    int col = n0 + wn + 16 * j + fr;
    float bias = pb[col];
#pragma unroll
    for (int i = 0; i < 2; ++i) {
      int rb2 = m0 + wm + 16 * i + fq * 4;
#pragma unroll
      for (int r = 0; r < 4; ++r)
        out[(size_t)(rb2 + r) * OUTd + col] = fast_tanh(acc[i][j][r] + bias);
    }
  }
}

extern "C" void kernel_launch(void* const* d_in, const int* in_sizes, int n_in,
                              void* d_out, int out_size, void* d_ws, size_t ws_size,
                              hipStream_t stream) {
  const float* obs   = (const float*)d_in[0];
  const int*   sw    = (const int*)d_in[1];
  const float* pre_w = (const float*)d_in[2];
  const float* pre_b = (const float*)d_in[3];
  const float* ew    = (const float*)d_in[4];
  const float* eb    = (const float*)d_in[5];
  const float* pw    = (const float*)d_in[6];
  const float* pb    = (const float*)d_in[7];
  float* out = (float*)d_out;

  char* ws = (char*)d_ws;
  int* offs = (int*)ws;
  int* rows = (int*)(ws + 128);
  u16* zeroc = (u16*)(ws + 128 + 16384);
  const size_t MISC = 65536;
  u16* X1     = (u16*)(ws + MISC);
  u16* Zb     = (u16*)(ws + MISC + ((size_t)16 << 20));
  u16* obsb   = (u16*)(ws + MISC + ((size_t)32 << 20));
  u16* prewb  = (u16*)(ws + MISC + ((size_t)40 << 20));
  u16* postwb = (u16*)(ws + MISC + ((size_t)44 << 20));
  u16* ewb    = (u16*)(ws + MISC + ((size_t)48 << 20));
  const size_t needMid  = MISC + ((size_t)48 << 20);
  const size_t needFull = needMid + ((size_t)128 << 20);
  const bool full = ws_size >= needFull;
  const bool mid  = ws_size >= needMid;

  k_bucket<<<dim3(1), dim3(256), 0, stream>>>(sw, offs, rows, (int*)zeroc);

  if (mid) {
    k_cvt<<<dim3(Bsz * INd / 2048), dim3(256), 0, stream>>>(obs, obsb, Bsz * INd);
    k_cvt<<<dim3(Hd * INd / 2048), dim3(256), 0, stream>>>(pre_w, prewb, Hd * INd);
    k_cvt<<<dim3(OUTd * Hd / 2048), dim3(256), 0, stream>>>(pw, postwb, OUTd * Hd);
  }
  if (full)
    k_cvt<<<dim3(NEXP * Hd * Hd / 2048), dim3(256), 0, stream>>>(ew, ewb, NEXP * Hd * Hd);

  if (mid)
    k_pre_t<true><<<dim3(Hd / 128, Bsz / 128), dim3(256), 0, stream>>>(obs, obsb, pre_w, prewb, pre_b, X1);
  else
    k_pre_t<false><<<dim3(Hd / 128, Bsz / 128), dim3(256), 0, stream>>>(obs, obsb, pre_w, prewb, pre_b, X1);

  if (full)
    k_expert_t<true><<<dim3(Hd / 128, NEXP * 32), dim3(256), 0, stream>>>(X1, ew, ewb, eb, offs, rows, zeroc, Zb);
  else
    k_expert_t<false><<<dim3(Hd / 128, NEXP * 32), dim3(256), 0, stream>>>(X1, ew, ewb, eb, offs, rows, zeroc, Zb);

  if (mid)
    k_post_t<true><<<dim3(OUTd / 128, Bsz / 64), dim3(256), 0, stream>>>(Zb, pw, postwb, pb, out);
  else
    k_post_t<false><<<dim3(OUTd / 128, Bsz / 64), dim3(256), 0, stream>>>(Zb, pw, postwb, pb, out);
}